// Round 4
// baseline (1687.087 us; speedup 1.0000x reference)
//
#include <hip/hip_runtime.h>
#include <stdint.h>
#include <math.h>

#define T_TOK 8192
#define DIM   2048
#define OUTD  2048
#define NEXP  8
#define NKT   (DIM / 32)          // 64 K-tiles of BK=32

typedef __bf16 bf16x8 __attribute__((ext_vector_type(8)));
typedef float  f32x4  __attribute__((ext_vector_type(4)));

// ---- bf16 helpers (manual RNE) ----
__device__ __forceinline__ unsigned short f2bf(float f) {
  union { float f; uint32_t u; } c = {f};
  uint32_t r = (c.u + 0x7FFFu + ((c.u >> 16) & 1u)) >> 16;
  return (unsigned short)r;
}
__device__ __forceinline__ float bf2f(unsigned short h) {
  union { uint32_t u; float f; } c = {((uint32_t)h) << 16};
  return c.f;
}

// ---- async global->LDS 16B ----
__device__ __forceinline__ void gld_lds16(const void* g, void* l) {
  auto gp = reinterpret_cast<const __attribute__((address_space(1))) char*>(
      reinterpret_cast<uintptr_t>(g));
  auto lp = reinterpret_cast<__attribute__((address_space(3))) char*>(
      reinterpret_cast<uintptr_t>(l));
  __builtin_amdgcn_global_load_lds(gp, lp, 16, 0, 0);
}

// ---- split fp32 -> bf16 hi/lo (expert weights only; x is split in router) ----
__global__ __launch_bounds__(256) void split_hi_lo(const float* __restrict__ src,
                                                   unsigned short* __restrict__ hi,
                                                   unsigned short* __restrict__ lo,
                                                   int n4) {
  int stride = gridDim.x * blockDim.x;
  for (int i = blockIdx.x * blockDim.x + threadIdx.x; i < n4; i += stride) {
    float4 v = reinterpret_cast<const float4*>(src)[i];
    ushort4 h, l;
    h.x = f2bf(v.x); l.x = f2bf(v.x - bf2f(h.x));
    h.y = f2bf(v.y); l.y = f2bf(v.y - bf2f(h.y));
    h.z = f2bf(v.z); l.z = f2bf(v.z - bf2f(h.z));
    h.w = f2bf(v.w); l.w = f2bf(v.w - bf2f(h.w));
    reinterpret_cast<ushort4*>(hi)[i] = h;
    reinterpret_cast<ushort4*>(lo)[i] = l;
  }
}

// ---- router (fp64-accum gate logits, top-2, softmax, scatter) + fused x split ----
__global__ __launch_bounds__(256) void router_split(const float* __restrict__ x,
                                                    const float* __restrict__ gw,
                                                    unsigned short* __restrict__ xh,
                                                    unsigned short* __restrict__ xl,
                                                    int* __restrict__ cnt,
                                                    int* __restrict__ tok_list,
                                                    float* __restrict__ tok_w) {
  const int t    = blockIdx.x * 4 + (threadIdx.x >> 6);  // one wave per token
  const int lane = threadIdx.x & 63;
  const float4* xr = reinterpret_cast<const float4*>(x + (size_t)t * DIM);
  ushort4* xhr = reinterpret_cast<ushort4*>(xh + (size_t)t * DIM);
  ushort4* xlr = reinterpret_cast<ushort4*>(xl + (size_t)t * DIM);
  double acc[NEXP];
#pragma unroll
  for (int e = 0; e < NEXP; ++e) acc[e] = 0.0;
#pragma unroll
  for (int i = 0; i < DIM / (4 * 64); ++i) {   // 8 iters
    float4 xv = xr[i * 64 + lane];
    ushort4 h, l;
    h.x = f2bf(xv.x); l.x = f2bf(xv.x - bf2f(h.x));
    h.y = f2bf(xv.y); l.y = f2bf(xv.y - bf2f(h.y));
    h.z = f2bf(xv.z); l.z = f2bf(xv.z - bf2f(h.z));
    h.w = f2bf(xv.w); l.w = f2bf(xv.w - bf2f(h.w));
    xhr[i * 64 + lane] = h;
    xlr[i * 64 + lane] = l;
#pragma unroll
    for (int e = 0; e < NEXP; ++e) {
      float4 gv = reinterpret_cast<const float4*>(gw + e * DIM)[i * 64 + lane];
      acc[e] += (double)xv.x * gv.x + (double)xv.y * gv.y +
                (double)xv.z * gv.z + (double)xv.w * gv.w;
    }
  }
#pragma unroll
  for (int off = 32; off >= 1; off >>= 1)
#pragma unroll
    for (int e = 0; e < NEXP; ++e) acc[e] += __shfl_down(acc[e], off, 64);
  if (lane == 0) {
    float lg[NEXP];
#pragma unroll
    for (int e = 0; e < NEXP; ++e) lg[e] = (float)acc[e];
    int i0 = 0; float v0 = lg[0];
    int i1 = -1; float v1 = -3.4e38f;
#pragma unroll
    for (int e = 1; e < NEXP; ++e) {
      if (lg[e] > v0)      { i1 = i0; v1 = v0; i0 = e; v0 = lg[e]; }
      else if (lg[e] > v1) { i1 = e;  v1 = lg[e]; }
    }
    float p  = expf(v1 - v0);
    float w0 = 1.0f / (1.0f + p);
    float w1 = p * w0;
    int s0 = atomicAdd(&cnt[i0], 1);
    tok_list[i0 * T_TOK + s0] = t; tok_w[i0 * T_TOK + s0] = w0;
    int s1 = atomicAdd(&cnt[i1], 1);
    tok_list[i1 * T_TOK + s1] = t; tok_w[i1 * T_TOK + s1] = w1;
  }
}

// ---- grouped expert GEMM v2: 256x256 tile, BK=32, 8 waves (2x4),
//      double-buffered 2-phase pipeline (stage next || compute cur),
//      XOR-swizzled LDS, bf16x2 split (xh*wh + xh*wl + xl*wh). ----
// LDS: buf0 @0 (A 32K | B 32K), buf1 @65536, stok @131072, sw @132096.
// Tile row layout: 128 B/row = 8 phys 16B slots; slot s<4 = hi k-slot s,
// s>=4 = lo k-slot s-4; phys p = s ^ (r&7).
__global__ __launch_bounds__(512, 2) void moe_gemm(
    const unsigned short* __restrict__ xh, const unsigned short* __restrict__ xl,
    const unsigned short* __restrict__ wh, const unsigned short* __restrict__ wl,
    const float* __restrict__ eb,
    const int* __restrict__ cnt,
    const int* __restrict__ tok_list, const float* __restrict__ tok_w,
    float* __restrict__ out) {
  const int e  = blockIdx.z;
  const int ce = cnt[e];
  const int bx = blockIdx.x;
  if (bx * 256 >= ce) return;
  const int by  = blockIdx.y;
  const int tid = threadIdx.x;
  const int l   = tid & 63;
  const int w   = tid >> 6;
  const int wr  = w >> 2, wc = w & 3;          // 2 x 4 waves, each owns 128x64 out

  extern __shared__ char smem[];
  int*   stok = reinterpret_cast<int*>(smem + 131072);
  float* sw   = reinterpret_cast<float*>(smem + 132096);

  if (tid < 256) {
    int rg = bx * 256 + tid;
    bool v = rg < ce;
    stok[tid] = v ? tok_list[e * T_TOK + rg] : 0;   // pad rows -> token 0
    sw[tid]   = v ? tok_w[e * T_TOK + rg]   : 0.0f; // pad rows -> weight 0
  }
  __syncthreads();

  // per-thread staging sources: 4 A granules + 4 B granules (16 B each)
  const unsigned short* asrc[4];
  const unsigned short* bsrc[4];
#pragma unroll
  for (int i = 0; i < 4; ++i) {
    int g = i * 512 + tid;
    int r = g >> 3, p = g & 7, s = p ^ (r & 7);
    asrc[i] = (s < 4 ? xh : xl) + (size_t)stok[r] * DIM + (s & 3) * 8;
    bsrc[i] = (s < 4 ? wh : wl) + ((size_t)e * OUTD + by * 256 + r) * DIM + (s & 3) * 8;
  }

  // per-lane ds_read byte offsets (r&7 == l&7 for all fragment rows)
  const int ph = (l >> 4) ^ (l & 7);           // hi: logical slot = l>>4
  const int pl = ((l >> 4) + 4) ^ (l & 7);     // lo: logical slot = 4 + (l>>4)
  const int aOh = (wr * 128 + (l & 15)) * 128 + ph * 16;
  const int aOl = (wr * 128 + (l & 15)) * 128 + pl * 16;
  const int bOh = 32768 + (wc * 64 + (l & 15)) * 128 + ph * 16;
  const int bOl = 32768 + (wc * 64 + (l & 15)) * 128 + pl * 16;

  f32x4 acc[8][4] = {};

  auto STAGE = [&](int buf, int kk) {
    char* base = smem + buf * 65536;
#pragma unroll
    for (int i = 0; i < 4; ++i) {
      gld_lds16(asrc[i] + kk, base + tid * 16 + i * 8192);
      gld_lds16(bsrc[i] + kk, base + 32768 + tid * 16 + i * 8192);
    }
  };

  STAGE(0, 0);
  asm volatile("s_waitcnt vmcnt(0)" ::: "memory");
  __syncthreads();

  for (int kt = 0; kt < NKT; ++kt) {
    const int cur = kt & 1;
    if (kt + 1 < NKT) STAGE(cur ^ 1, (kt + 1) * 32);   // prefetch in flight during MFMA

    char* b = smem + cur * 65536;
    bf16x8 bh[4], bl[4];
#pragma unroll
    for (int n = 0; n < 4; ++n) {
      bh[n] = *reinterpret_cast<const bf16x8*>(b + bOh + n * 2048);
      bl[n] = *reinterpret_cast<const bf16x8*>(b + bOl + n * 2048);
    }
#pragma unroll
    for (int m = 0; m < 8; ++m) {
      bf16x8 ah = *reinterpret_cast<const bf16x8*>(b + aOh + m * 2048);
      bf16x8 al = *reinterpret_cast<const bf16x8*>(b + aOl + m * 2048);
#pragma unroll
      for (int n = 0; n < 4; ++n) {
        acc[m][n] = __builtin_amdgcn_mfma_f32_16x16x32_bf16(ah, bh[n], acc[m][n], 0, 0, 0);
        acc[m][n] = __builtin_amdgcn_mfma_f32_16x16x32_bf16(ah, bl[n], acc[m][n], 0, 0, 0);
        acc[m][n] = __builtin_amdgcn_mfma_f32_16x16x32_bf16(al, bh[n], acc[m][n], 0, 0, 0);
      }
    }
    asm volatile("s_waitcnt vmcnt(0)" ::: "memory");
    __syncthreads();                                    // one barrier per K-tile
  }

  // epilogue: out[tok][gc] += wt * (acc + bias)
#pragma unroll
  for (int n = 0; n < 4; ++n) {
    const int gc = by * 256 + wc * 64 + n * 16 + (l & 15);
    const float bias = eb[e * OUTD + gc];
#pragma unroll
    for (int m = 0; m < 8; ++m) {
      const int r = wr * 128 + m * 16 + (l >> 4) * 4;
#pragma unroll
      for (int q = 0; q < 4; ++q) {
        int   tk = stok[r + q];
        float wt = sw[r + q];
        float val = wt * (acc[m][n][q] + bias);
        atomicAdd(out + (size_t)tk * OUTD + gc, val);
      }
    }
  }
}

// Hoist the LDS-size attribute out of kernel_launch: runs once at dlopen,
// BEFORE any graph capture, so kernel_launch contains only stream ops.
__attribute__((constructor)) static void set_lds_attr() {
  hipFuncSetAttribute((const void*)moe_gemm,
                      hipFuncAttributeMaxDynamicSharedMemorySize, 133120);
}

extern "C" void kernel_launch(void* const* d_in, const int* in_sizes, int n_in,
                              void* d_out, int out_size, void* d_ws, size_t ws_size,
                              hipStream_t stream) {
  const float* x  = (const float*)d_in[0];   // [2,4096,2048]
  const float* gw = (const float*)d_in[1];   // [8,2048]
  const float* ew = (const float*)d_in[2];   // [8,2048,2048]
  const float* eb = (const float*)d_in[3];   // [8,2048]
  float* out = (float*)d_out;                // [2,4096,2048]

  char* ws = (char*)d_ws;
  int*   cnt      = (int*)(ws);                          // 32 B (pad 256)
  int*   tok_list = (int*)(ws + 256);                    // 256 KiB
  float* tok_w    = (float*)(ws + 256 + 262144);         // 256 KiB
  unsigned short* xh = (unsigned short*)(ws + 524544);   // 32 MiB
  unsigned short* xl = xh + 16777216;                    // 32 MiB
  unsigned short* wh = xl + 16777216;                    // 64 MiB
  unsigned short* wl = wh + 33554432;                    // 64 MiB

  hipMemsetAsync(cnt, 0, 256, stream);
  hipMemsetAsync(d_out, 0, (size_t)out_size * sizeof(float), stream);

  split_hi_lo<<<4096, 256, 0, stream>>>(ew, wh, wl, 33554432 / 4);
  router_split<<<T_TOK / 4, 256, 0, stream>>>(x, gw, xh, xl, cnt, tok_list, tok_w);

  // worst case: one expert owns all 8192 tokens -> 32 row-blocks; inactive exit early
  moe_gemm<<<dim3(32, 8, 8), 512, 133120, stream>>>(xh, xl, wh, wl, eb, cnt,
                                                    tok_list, tok_w, out);
}

// Round 7
// 1080.051 us; speedup vs baseline: 1.5620x; 1.5620x over previous
//
#include <hip/hip_runtime.h>
#include <stdint.h>
#include <math.h>

#define T_TOK 8192
#define DIM   2048
#define OUTD  2048
#define NEXP  8
#define NKT   (DIM / 32)          // 64 K-tiles of BK=32

typedef __bf16 bf16x8 __attribute__((ext_vector_type(8)));
typedef float  f32x4  __attribute__((ext_vector_type(4)));

// ---- bf16 helpers (manual RNE) ----
__device__ __forceinline__ unsigned short f2bf(float f) {
  union { float f; uint32_t u; } c = {f};
  uint32_t r = (c.u + 0x7FFFu + ((c.u >> 16) & 1u)) >> 16;
  return (unsigned short)r;
}
__device__ __forceinline__ float bf2f(unsigned short h) {
  union { uint32_t u; float f; } c = {((uint32_t)h) << 16};
  return c.f;
}

// ---- async global->LDS 16B ----
__device__ __forceinline__ void gld_lds16(const void* g, void* l) {
  auto gp = reinterpret_cast<const __attribute__((address_space(1))) char*>(
      reinterpret_cast<uintptr_t>(g));
  auto lp = reinterpret_cast<__attribute__((address_space(3))) char*>(
      reinterpret_cast<uintptr_t>(l));
  __builtin_amdgcn_global_load_lds(gp, lp, 16, 0, 0);
}

// ---- split fp32 -> bf16 hi/lo (expert weights only; x is split in router) ----
__global__ __launch_bounds__(256) void split_hi_lo(const float* __restrict__ src,
                                                   unsigned short* __restrict__ hi,
                                                   unsigned short* __restrict__ lo,
                                                   int n4) {
  int stride = gridDim.x * blockDim.x;
  for (int i = blockIdx.x * blockDim.x + threadIdx.x; i < n4; i += stride) {
    float4 v = reinterpret_cast<const float4*>(src)[i];
    ushort4 h, l;
    h.x = f2bf(v.x); l.x = f2bf(v.x - bf2f(h.x));
    h.y = f2bf(v.y); l.y = f2bf(v.y - bf2f(h.y));
    h.z = f2bf(v.z); l.z = f2bf(v.z - bf2f(h.z));
    h.w = f2bf(v.w); l.w = f2bf(v.w - bf2f(h.w));
    reinterpret_cast<ushort4*>(hi)[i] = h;
    reinterpret_cast<ushort4*>(lo)[i] = l;
  }
}

// ---- router (fp64-accum gate logits, top-2, softmax, scatter) + fused x split ----
__global__ __launch_bounds__(256) void router_split(const float* __restrict__ x,
                                                    const float* __restrict__ gw,
                                                    unsigned short* __restrict__ xh,
                                                    unsigned short* __restrict__ xl,
                                                    int* __restrict__ cnt,
                                                    int* __restrict__ tok_list,
                                                    float* __restrict__ tok_w) {
  const int t    = blockIdx.x * 4 + (threadIdx.x >> 6);  // one wave per token
  const int lane = threadIdx.x & 63;
  const float4* xr = reinterpret_cast<const float4*>(x + (size_t)t * DIM);
  ushort4* xhr = reinterpret_cast<ushort4*>(xh + (size_t)t * DIM);
  ushort4* xlr = reinterpret_cast<ushort4*>(xl + (size_t)t * DIM);
  double acc[NEXP];
#pragma unroll
  for (int e = 0; e < NEXP; ++e) acc[e] = 0.0;
#pragma unroll
  for (int i = 0; i < DIM / (4 * 64); ++i) {   // 8 iters
    float4 xv = xr[i * 64 + lane];
    ushort4 h, l;
    h.x = f2bf(xv.x); l.x = f2bf(xv.x - bf2f(h.x));
    h.y = f2bf(xv.y); l.y = f2bf(xv.y - bf2f(h.y));
    h.z = f2bf(xv.z); l.z = f2bf(xv.z - bf2f(h.z));
    h.w = f2bf(xv.w); l.w = f2bf(xv.w - bf2f(h.w));
    xhr[i * 64 + lane] = h;
    xlr[i * 64 + lane] = l;
#pragma unroll
    for (int e = 0; e < NEXP; ++e) {
      float4 gv = reinterpret_cast<const float4*>(gw + e * DIM)[i * 64 + lane];
      acc[e] += (double)xv.x * gv.x + (double)xv.y * gv.y +
                (double)xv.z * gv.z + (double)xv.w * gv.w;
    }
  }
#pragma unroll
  for (int off = 32; off >= 1; off >>= 1)
#pragma unroll
    for (int e = 0; e < NEXP; ++e) acc[e] += __shfl_down(acc[e], off, 64);
  if (lane == 0) {
    float lg[NEXP];
#pragma unroll
    for (int e = 0; e < NEXP; ++e) lg[e] = (float)acc[e];
    int i0 = 0; float v0 = lg[0];
    int i1 = -1; float v1 = -3.4e38f;
#pragma unroll
    for (int e = 1; e < NEXP; ++e) {
      if (lg[e] > v0)      { i1 = i0; v1 = v0; i0 = e; v0 = lg[e]; }
      else if (lg[e] > v1) { i1 = e;  v1 = lg[e]; }
    }
    float p  = expf(v1 - v0);
    float w0 = 1.0f / (1.0f + p);
    float w1 = p * w0;
    int s0 = atomicAdd(&cnt[i0], 1);
    tok_list[i0 * T_TOK + s0] = t; tok_w[i0 * T_TOK + s0] = w0;
    int s1 = atomicAdd(&cnt[i1], 1);
    tok_list[i1 * T_TOK + s1] = t; tok_w[i1 * T_TOK + s1] = w1;
  }
}

// ---- grouped expert GEMM v3: 256x256 tile, BK=32, 8 waves (2x4),
//      double-buffered with COUNTED vmcnt(8) (loads span a full iteration,
//      never drained to 0 in the main loop) + raw s_barrier (no implicit
//      vmcnt(0) reinsertion). Compact 1-D grid: block gid -> (rb, by) with
//      by fastest; (e, bx) from on-the-fly prefix over cnt[] so active
//      blocks are dense and weight reuse stays L3-resident. ----
// LDS: buf0 @0 (A 32K | B 32K), buf1 @65536, stok @131072, sw @132096.
// Tile row layout: 128 B/row = 8 phys 16B slots; slot s<4 = hi k-slot s,
// s>=4 = lo k-slot s-4; phys p = s ^ (r&7).
__global__ __launch_bounds__(512, 2) void moe_gemm(
    const unsigned short* __restrict__ xh, const unsigned short* __restrict__ xl,
    const unsigned short* __restrict__ wh, const unsigned short* __restrict__ wl,
    const float* __restrict__ eb,
    const int* __restrict__ cnt,
    const int* __restrict__ tok_list, const float* __restrict__ tok_w,
    float* __restrict__ out) {
  // ---- compact block id -> (e, bx, by) ----
  const int gid = blockIdx.x;
  const int by  = gid & 7;          // fastest: 8 by-blocks share one A-slice
  const int rb  = gid >> 3;         // global row-block over concat'd experts
  int e = 0, off = 0, ce = 0;
#pragma unroll
  for (int ee = 0; ee < NEXP; ++ee) {
    int c  = cnt[ee];
    int nb = (c + 255) >> 8;
    if (rb >= off && rb < off + nb && ce == 0) { e = ee; ce = c; }
    off += (rb >= off + nb && ce == 0) ? nb : 0;
  }
  if (ce == 0) return;              // rb beyond total active row-blocks
  const int bx = rb - off;

  const int tid = threadIdx.x;
  const int l   = tid & 63;
  const int w   = tid >> 6;
  const int wr  = w >> 2, wc = w & 3;          // 2 x 4 waves, each owns 128x64 out

  extern __shared__ char smem[];
  int*   stok = reinterpret_cast<int*>(smem + 131072);
  float* sw   = reinterpret_cast<float*>(smem + 132096);

  if (tid < 256) {
    int rg = bx * 256 + tid;
    bool v = rg < ce;
    stok[tid] = v ? tok_list[e * T_TOK + rg] : 0;   // pad rows -> token 0
    sw[tid]   = v ? tok_w[e * T_TOK + rg]   : 0.0f; // pad rows -> weight 0
  }
  __syncthreads();

  // per-thread staging sources: 4 A granules + 4 B granules (16 B each)
  const unsigned short* asrc[4];
  const unsigned short* bsrc[4];
#pragma unroll
  for (int i = 0; i < 4; ++i) {
    int g = i * 512 + tid;
    int r = g >> 3, p = g & 7, s = p ^ (r & 7);
    asrc[i] = (s < 4 ? xh : xl) + (size_t)stok[r] * DIM + (s & 3) * 8;
    bsrc[i] = (s < 4 ? wh : wl) + ((size_t)e * OUTD + by * 256 + r) * DIM + (s & 3) * 8;
  }

  // per-lane ds_read byte offsets (r&7 == l&7 for all fragment rows)
  const int ph = (l >> 4) ^ (l & 7);           // hi: logical slot = l>>4
  const int pl = ((l >> 4) + 4) ^ (l & 7);     // lo: logical slot = 4 + (l>>4)
  const int aOh = (wr * 128 + (l & 15)) * 128 + ph * 16;
  const int aOl = (wr * 128 + (l & 15)) * 128 + pl * 16;
  const int bOh = 32768 + (wc * 64 + (l & 15)) * 128 + ph * 16;
  const int bOl = 32768 + (wc * 64 + (l & 15)) * 128 + pl * 16;

  f32x4 acc[8][4] = {};

  auto STAGE = [&](int buf, int kk) {
    char* base = smem + buf * 65536;
#pragma unroll
    for (int i = 0; i < 4; ++i) {
      gld_lds16(asrc[i] + kk, base + tid * 16 + i * 8192);
      gld_lds16(bsrc[i] + kk, base + 32768 + tid * 16 + i * 8192);
    }
  };

  STAGE(0, 0);                                  // 8 loads in flight

  for (int kt = 0; kt < NKT; ++kt) {
    const int cur = kt & 1;
    if (kt + 1 < NKT) {
      STAGE(cur ^ 1, (kt + 1) * 32);            // +8 loads (tile kt+1)
      // wait for tile kt's 8 loads (oldest); leave kt+1's 8 in flight
      asm volatile("s_waitcnt vmcnt(8)" ::: "memory");
    } else {
      asm volatile("s_waitcnt vmcnt(0)" ::: "memory");
    }
    __builtin_amdgcn_s_barrier();               // raw: no implicit vmcnt(0)
    __builtin_amdgcn_sched_barrier(0);          // keep ds_reads below barrier

    char* b = smem + cur * 65536;
    bf16x8 bh[4], bl[4];
#pragma unroll
    for (int n = 0; n < 4; ++n) {
      bh[n] = *reinterpret_cast<const bf16x8*>(b + bOh + n * 2048);
      bl[n] = *reinterpret_cast<const bf16x8*>(b + bOl + n * 2048);
    }
#pragma unroll
    for (int m = 0; m < 8; ++m) {
      bf16x8 ah = *reinterpret_cast<const bf16x8*>(b + aOh + m * 2048);
      bf16x8 al = *reinterpret_cast<const bf16x8*>(b + aOl + m * 2048);
#pragma unroll
      for (int n = 0; n < 4; ++n) {
        acc[m][n] = __builtin_amdgcn_mfma_f32_16x16x32_bf16(ah, bh[n], acc[m][n], 0, 0, 0);
        acc[m][n] = __builtin_amdgcn_mfma_f32_16x16x32_bf16(ah, bl[n], acc[m][n], 0, 0, 0);
        acc[m][n] = __builtin_amdgcn_mfma_f32_16x16x32_bf16(al, bh[n], acc[m][n], 0, 0, 0);
      }
    }
    __builtin_amdgcn_sched_barrier(0);          // keep ds_reads above barrier
    __builtin_amdgcn_s_barrier();               // buf safe to overwrite next iter
  }

  // epilogue: out[tok][gc] += wt * (acc + bias)
#pragma unroll
  for (int n = 0; n < 4; ++n) {
    const int gc = by * 256 + wc * 64 + n * 16 + (l & 15);
    const float bias = eb[e * OUTD + gc];
#pragma unroll
    for (int m = 0; m < 8; ++m) {
      const int r = wr * 128 + m * 16 + (l >> 4) * 4;
#pragma unroll
      for (int q = 0; q < 4; ++q) {
        int   tk = stok[r + q];
        float wt = sw[r + q];
        float val = wt * (acc[m][n][q] + bias);
        atomicAdd(out + (size_t)tk * OUTD + gc, val);
      }
    }
  }
}

// Hoist the LDS-size attribute out of kernel_launch: runs once at dlopen,
// BEFORE any graph capture, so kernel_launch contains only stream ops.
__attribute__((constructor)) static void set_lds_attr() {
  hipFuncSetAttribute((const void*)moe_gemm,
                      hipFuncAttributeMaxDynamicSharedMemorySize, 133120);
}

extern "C" void kernel_launch(void* const* d_in, const int* in_sizes, int n_in,
                              void* d_out, int out_size, void* d_ws, size_t ws_size,
                              hipStream_t stream) {
  const float* x  = (const float*)d_in[0];   // [2,4096,2048]
  const float* gw = (const float*)d_in[1];   // [8,2048]
  const float* ew = (const float*)d_in[2];   // [8,2048,2048]
  const float* eb = (const float*)d_in[3];   // [8,2048]
  float* out = (float*)d_out;                // [2,4096,2048]

  char* ws = (char*)d_ws;
  int*   cnt      = (int*)(ws);                          // 32 B (pad 256)
  int*   tok_list = (int*)(ws + 256);                    // 256 KiB
  float* tok_w    = (float*)(ws + 256 + 262144);         // 256 KiB
  unsigned short* xh = (unsigned short*)(ws + 524544);   // 32 MiB
  unsigned short* xl = xh + 16777216;                    // 32 MiB
  unsigned short* wh = xl + 16777216;                    // 64 MiB
  unsigned short* wl = wh + 33554432;                    // 64 MiB

  hipMemsetAsync(cnt, 0, 256, stream);
  hipMemsetAsync(d_out, 0, (size_t)out_size * sizeof(float), stream);

  split_hi_lo<<<4096, 256, 0, stream>>>(ew, wh, wl, 33554432 / 4);
  router_split<<<T_TOK / 4, 256, 0, stream>>>(x, gw, xh, xl, cnt, tok_list, tok_w);

  // compact grid: 72 worst-case row-blocks (sum ceil(ce/256) <= 64+8) x 8 by
  moe_gemm<<<dim3(576), 512, 133120, stream>>>(xh, xl, wh, wl, eb, cnt,
                                               tok_list, tok_w, out);
}

// Round 9
// 1014.467 us; speedup vs baseline: 1.6630x; 1.0646x over previous
//
#include <hip/hip_runtime.h>
#include <stdint.h>
#include <math.h>

#define T_TOK 8192
#define DIM   2048
#define OUTD  2048
#define NEXP  8
#define NKT   (DIM / 32)          // 64 K-tiles of BK=32
#define BM    288                 // 9 m-blocks/wave; ceil(2048/288)=8 -> 512 items = 2.0 rounds
#define NGRAN (BM * 8 + 2048)     // 4352 granules: A 2304 + B 2048
// LDS map: buf stride 69632 (A 36864 | B 32768), buf1 @69632,
//          stok @139264 (1152 B), sw @140416 (1152 B), total 141568.

typedef __bf16 bf16x8 __attribute__((ext_vector_type(8)));
typedef float  f32x4  __attribute__((ext_vector_type(4)));

// ---- bf16 helpers (manual RNE) ----
__device__ __forceinline__ unsigned short f2bf(float f) {
  union { float f; uint32_t u; } c = {f};
  uint32_t r = (c.u + 0x7FFFu + ((c.u >> 16) & 1u)) >> 16;
  return (unsigned short)r;
}
__device__ __forceinline__ float bf2f(unsigned short h) {
  union { uint32_t u; float f; } c = {((uint32_t)h) << 16};
  return c.f;
}

// ---- async global->LDS 16B ----
__device__ __forceinline__ void gld_lds16(const void* g, void* l) {
  auto gp = reinterpret_cast<const __attribute__((address_space(1))) char*>(
      reinterpret_cast<uintptr_t>(g));
  auto lp = reinterpret_cast<__attribute__((address_space(3))) char*>(
      reinterpret_cast<uintptr_t>(l));
  __builtin_amdgcn_global_load_lds(gp, lp, 16, 0, 0);
}

// ---- split fp32 -> bf16 hi/lo (expert weights only; x is split in router) ----
__global__ __launch_bounds__(256) void split_hi_lo(const float* __restrict__ src,
                                                   unsigned short* __restrict__ hi,
                                                   unsigned short* __restrict__ lo,
                                                   int n4) {
  int stride = gridDim.x * blockDim.x;
  for (int i = blockIdx.x * blockDim.x + threadIdx.x; i < n4; i += stride) {
    float4 v = reinterpret_cast<const float4*>(src)[i];
    ushort4 h, l;
    h.x = f2bf(v.x); l.x = f2bf(v.x - bf2f(h.x));
    h.y = f2bf(v.y); l.y = f2bf(v.y - bf2f(h.y));
    h.z = f2bf(v.z); l.z = f2bf(v.z - bf2f(h.z));
    h.w = f2bf(v.w); l.w = f2bf(v.w - bf2f(h.w));
    reinterpret_cast<ushort4*>(hi)[i] = h;
    reinterpret_cast<ushort4*>(lo)[i] = l;
  }
}

// ---- router (fp64-accum gate logits, top-2, softmax, scatter) + fused x split ----
__global__ __launch_bounds__(256) void router_split(const float* __restrict__ x,
                                                    const float* __restrict__ gw,
                                                    unsigned short* __restrict__ xh,
                                                    unsigned short* __restrict__ xl,
                                                    int* __restrict__ cnt,
                                                    int* __restrict__ tok_list,
                                                    float* __restrict__ tok_w) {
  const int t    = blockIdx.x * 4 + (threadIdx.x >> 6);  // one wave per token
  const int lane = threadIdx.x & 63;
  const float4* xr = reinterpret_cast<const float4*>(x + (size_t)t * DIM);
  ushort4* xhr = reinterpret_cast<ushort4*>(xh + (size_t)t * DIM);
  ushort4* xlr = reinterpret_cast<ushort4*>(xl + (size_t)t * DIM);
  double acc[NEXP];
#pragma unroll
  for (int e = 0; e < NEXP; ++e) acc[e] = 0.0;
#pragma unroll
  for (int i = 0; i < DIM / (4 * 64); ++i) {   // 8 iters
    float4 xv = xr[i * 64 + lane];
    ushort4 h, l;
    h.x = f2bf(xv.x); l.x = f2bf(xv.x - bf2f(h.x));
    h.y = f2bf(xv.y); l.y = f2bf(xv.y - bf2f(h.y));
    h.z = f2bf(xv.z); l.z = f2bf(xv.z - bf2f(h.z));
    h.w = f2bf(xv.w); l.w = f2bf(xv.w - bf2f(h.w));
    xhr[i * 64 + lane] = h;
    xlr[i * 64 + lane] = l;
#pragma unroll
    for (int e = 0; e < NEXP; ++e) {
      float4 gv = reinterpret_cast<const float4*>(gw + e * DIM)[i * 64 + lane];
      acc[e] += (double)xv.x * gv.x + (double)xv.y * gv.y +
                (double)xv.z * gv.z + (double)xv.w * gv.w;
    }
  }
#pragma unroll
  for (int off = 32; off >= 1; off >>= 1)
#pragma unroll
    for (int e = 0; e < NEXP; ++e) acc[e] += __shfl_down(acc[e], off, 64);
  if (lane == 0) {
    float lg[NEXP];
#pragma unroll
    for (int e = 0; e < NEXP; ++e) lg[e] = (float)acc[e];
    int i0 = 0; float v0 = lg[0];
    int i1 = -1; float v1 = -3.4e38f;
#pragma unroll
    for (int e = 1; e < NEXP; ++e) {
      if (lg[e] > v0)      { i1 = i0; v1 = v0; i0 = e; v0 = lg[e]; }
      else if (lg[e] > v1) { i1 = e;  v1 = lg[e]; }
    }
    float p  = expf(v1 - v0);
    float w0 = 1.0f / (1.0f + p);
    float w1 = p * w0;
    int s0 = atomicAdd(&cnt[i0], 1);
    tok_list[i0 * T_TOK + s0] = t; tok_w[i0 * T_TOK + s0] = w0;
    int s1 = atomicAdd(&cnt[i1], 1);
    tok_list[i1 * T_TOK + s1] = t; tok_w[i1 * T_TOK + s1] = w1;
  }
}

// ---- grouped expert GEMM v4b: 288x256 tile (tail-free: 512 items = 2.0 rounds),
//      BK=32, 8 waves (2x4, each 144x64 out), double-buffered counted-vmcnt
//      pipeline + phase-interleaved ds_read/MFMA with setprio.
//      (v4 compile fix: B fragments declared BEFORE the MM lambda.) ----
__global__ __launch_bounds__(512, 2) void moe_gemm(
    const unsigned short* __restrict__ xh, const unsigned short* __restrict__ xl,
    const unsigned short* __restrict__ wh, const unsigned short* __restrict__ wl,
    const float* __restrict__ eb,
    const int* __restrict__ cnt,
    const int* __restrict__ tok_list, const float* __restrict__ tok_w,
    float* __restrict__ out) {
  // ---- compact block id -> (e, bx, by); by fastest ----
  const int gid = blockIdx.x;
  const int by  = gid & 7;
  const int rb  = gid >> 3;
  int e = 0, off = 0, ce = 0;
#pragma unroll
  for (int ee = 0; ee < NEXP; ++ee) {
    int c  = cnt[ee];
    int nb = (c + (BM - 1)) / BM;
    if (rb >= off && rb < off + nb && ce == 0) { e = ee; ce = c; }
    off += (rb >= off + nb && ce == 0) ? nb : 0;
  }
  if (ce == 0) return;              // block-uniform exit (no barriers crossed)
  const int bx = rb - off;

  const int tid = threadIdx.x;
  const int l   = tid & 63;
  const int w   = tid >> 6;
  const int wr  = w >> 2, wc = w & 3;

  extern __shared__ char smem[];
  int*   stok = reinterpret_cast<int*>(smem + 139264);
  float* sw   = reinterpret_cast<float*>(smem + 140416);

  if (tid < BM) {
    int rg = bx * BM + tid;
    bool v = rg < ce;
    stok[tid] = v ? tok_list[e * T_TOK + rg] : 0;   // pad rows -> token 0
    sw[tid]   = v ? tok_w[e * T_TOK + rg]   : 0.0f; // pad rows -> weight 0
  }
  __syncthreads();

  // staging byte-offsets from xh (ws regions contiguous: xh|xl|wh|wl)
  // granule g: A (g<2304): row r=g>>3, phys p=g&7, logical s=p^(r&7);
  //            B: gb=g-2304 likewise. LDS dst = g*16 (B base 36864 = 2304*16).
  const char* wsbase = (const char*)xh;
  uint32_t goff[9];
#pragma unroll
  for (int i = 0; i < 9; ++i) {
    int g = i * 512 + tid;
    if (g < BM * 8) {
      int r = g >> 3, p = g & 7, s = p ^ (r & 7);
      goff[i] = (s < 4 ? 0u : 33554432u) +
                ((uint32_t)stok[r] * DIM + (s & 3) * 8) * 2u;
    } else if (g < NGRAN) {
      int gb = g - BM * 8;
      int r = gb >> 3, p = gb & 7, s = p ^ (r & 7);
      goff[i] = (s < 4 ? 67108864u : 134217728u) +
                (((uint32_t)e * OUTD + by * 256 + r) * DIM + (s & 3) * 8) * 2u;
    } else goff[i] = 0;
  }
  __syncthreads();   // all stok reads done before any staging could land

  // per-lane ds_read byte offsets (row low bits = l&15 -> r&7 == l&7)
  const int ph  = (l >> 4) ^ (l & 7);
  const int pl  = ((l >> 4) + 4) ^ (l & 7);
  const int aOh = (wr * 144 + (l & 15)) * 128 + ph * 16;
  const int aOl = (wr * 144 + (l & 15)) * 128 + pl * 16;
  const int bOh = 36864 + (wc * 64 + (l & 15)) * 128 + ph * 16;
  const int bOl = 36864 + (wc * 64 + (l & 15)) * 128 + pl * 16;

  f32x4 acc[9][4] = {};

  auto STAGE = [&](int buf, int kt1) {
    char* base = smem + buf * 69632 + tid * 16;
    const char* gb = wsbase + kt1 * 64;          // BK=32 -> 64 B per K-tile
#pragma unroll
    for (int i = 0; i < 9; ++i) {
      int g = i * 512 + tid;
      if (g < NGRAN)                             // i==8 skip is wave-uniform
        gld_lds16(gb + goff[i], base + i * 8192);
    }
  };

  STAGE(0, 0);

  for (int kt = 0; kt < NKT; ++kt) {
    const int cur = kt & 1;
    if (kt + 1 < NKT) {
      STAGE(cur ^ 1, kt + 1);
      // retire exactly this tile's loads (issued last iter); keep next tile's in flight
      if (w < 4) asm volatile("s_waitcnt vmcnt(9)" ::: "memory");
      else       asm volatile("s_waitcnt vmcnt(8)" ::: "memory");
    } else {
      asm volatile("s_waitcnt vmcnt(0)" ::: "memory");
    }
    __builtin_amdgcn_s_barrier();
    __builtin_amdgcn_sched_barrier(0);

    const char* b = smem + cur * 69632;
    auto LD = [&](int o) { return *reinterpret_cast<const bf16x8*>(b + o); };

    bf16x8 bhv[4], blv[4];                       // declared BEFORE MM (v4 fix)
#pragma unroll
    for (int n = 0; n < 4; ++n) {
      bhv[n] = LD(bOh + n * 2048);
      blv[n] = LD(bOl + n * 2048);
    }
    auto MM = [&](bf16x8 ah, bf16x8 al, int m) {
#pragma unroll
      for (int n = 0; n < 4; ++n) {
        acc[m][n] = __builtin_amdgcn_mfma_f32_16x16x32_bf16(ah, bhv[n], acc[m][n], 0, 0, 0);
        acc[m][n] = __builtin_amdgcn_mfma_f32_16x16x32_bf16(ah, blv[n], acc[m][n], 0, 0, 0);
        acc[m][n] = __builtin_amdgcn_mfma_f32_16x16x32_bf16(al, bhv[n], acc[m][n], 0, 0, 0);
      }
    };

    // rotating 2-pair register window: read pair k+1 while MFMA'ing pair k
    bf16x8 c0h = LD(aOh),            c0l = LD(aOl);
    bf16x8 c1h = LD(aOh + 2048),     c1l = LD(aOl + 2048);
    bf16x8 n0h = LD(aOh + 2 * 2048), n0l = LD(aOl + 2 * 2048);
    bf16x8 n1h = LD(aOh + 3 * 2048), n1l = LD(aOl + 3 * 2048);
    __builtin_amdgcn_s_setprio(1); MM(c0h, c0l, 0); MM(c1h, c1l, 1); __builtin_amdgcn_s_setprio(0);
    c0h = LD(aOh + 4 * 2048); c0l = LD(aOl + 4 * 2048);
    c1h = LD(aOh + 5 * 2048); c1l = LD(aOl + 5 * 2048);
    __builtin_amdgcn_s_setprio(1); MM(n0h, n0l, 2); MM(n1h, n1l, 3); __builtin_amdgcn_s_setprio(0);
    n0h = LD(aOh + 6 * 2048); n0l = LD(aOl + 6 * 2048);
    n1h = LD(aOh + 7 * 2048); n1l = LD(aOl + 7 * 2048);
    __builtin_amdgcn_s_setprio(1); MM(c0h, c0l, 4); MM(c1h, c1l, 5); __builtin_amdgcn_s_setprio(0);
    c0h = LD(aOh + 8 * 2048); c0l = LD(aOl + 8 * 2048);
    __builtin_amdgcn_s_setprio(1); MM(n0h, n0l, 6); MM(n1h, n1l, 7); __builtin_amdgcn_s_setprio(0);
    __builtin_amdgcn_s_setprio(1); MM(c0h, c0l, 8); __builtin_amdgcn_s_setprio(0);

    __builtin_amdgcn_sched_barrier(0);    // all ds_reads consumed above this line
    __builtin_amdgcn_s_barrier();         // buffer safe to overwrite next iter
  }

  // epilogue: out[tok][gc] += wt * (acc + bias)
#pragma unroll
  for (int n = 0; n < 4; ++n) {
    const int gc = by * 256 + wc * 64 + n * 16 + (l & 15);
    const float bias = eb[e * OUTD + gc];
#pragma unroll
    for (int m = 0; m < 9; ++m) {
      const int r = wr * 144 + m * 16 + (l >> 4) * 4;
#pragma unroll
      for (int q = 0; q < 4; ++q) {
        int   tk = stok[r + q];
        float wt = sw[r + q];
        float val = wt * (acc[m][n][q] + bias);
        atomicAdd(out + (size_t)tk * OUTD + gc, val);
      }
    }
  }
}

// LDS-size attribute at dlopen (before graph capture).
__attribute__((constructor)) static void set_lds_attr() {
  hipFuncSetAttribute((const void*)moe_gemm,
                      hipFuncAttributeMaxDynamicSharedMemorySize, 141568);
}

extern "C" void kernel_launch(void* const* d_in, const int* in_sizes, int n_in,
                              void* d_out, int out_size, void* d_ws, size_t ws_size,
                              hipStream_t stream) {
  const float* x  = (const float*)d_in[0];   // [2,4096,2048]
  const float* gw = (const float*)d_in[1];   // [8,2048]
  const float* ew = (const float*)d_in[2];   // [8,2048,2048]
  const float* eb = (const float*)d_in[3];   // [8,2048]
  float* out = (float*)d_out;                // [2,4096,2048]

  char* ws = (char*)d_ws;
  int*   cnt      = (int*)(ws);                          // 32 B (pad 256)
  int*   tok_list = (int*)(ws + 256);                    // 256 KiB
  float* tok_w    = (float*)(ws + 256 + 262144);         // 256 KiB
  unsigned short* xh = (unsigned short*)(ws + 524544);   // 32 MiB  (xh|xl|wh|wl contiguous)
  unsigned short* xl = xh + 16777216;                    // 32 MiB
  unsigned short* wh = xl + 16777216;                    // 64 MiB
  unsigned short* wl = wh + 33554432;                    // 64 MiB

  hipMemsetAsync(cnt, 0, 256, stream);
  hipMemsetAsync(d_out, 0, (size_t)out_size * sizeof(float), stream);

  split_hi_lo<<<4096, 256, 0, stream>>>(ew, wh, wl, 33554432 / 4);
  router_split<<<T_TOK / 4, 256, 0, stream>>>(x, gw, xh, xl, cnt, tok_list, tok_w);

  // 64 worst-case row-blocks (sum ceil(ce/288) <= floor(16384/288)+8 = 64) x 8 by
  moe_gemm<<<dim3(512), 512, 141568, stream>>>(xh, xl, wh, wl, eb, cnt,
                                               tok_list, tok_w, out);
}